// Round 9
// baseline (1120.001 us; speedup 1.0000x reference)
//
#include <hip/hip_runtime.h>

// Problem dims (fixed by the reference)
#define BB 4        // batch
#define CC 4096     // channels
#define TT 2048     // timesteps
#define BS 16       // block size
#define KK 100      // IRF taps
#define NNZ 1024    // nonzero blocks
#define NB (CC / BS)
#define MAXM 64     // max blocks per output row

// ---------------- ws layout ----------------
#define WS_CNT   0u
#define WS_PERM  1024u
#define WS_LIST  2048u
#define WS_XT    1048576u                       // 1 MB, 16B-aligned
#define XT_BYTES (134217728u)                   // B*NB*512*16 float4 = 128 MB
#define WS_NEED  ((size_t)WS_XT + XT_BYTES)

// acc + DPP-permuted src (GCNDPPCombine fuses mov_dpp+add -> v_add_f32_dpp)
template <int CTRL>
__device__ __forceinline__ float add_dpp(float acc, float src) {
    int m = __builtin_amdgcn_update_dpp(0, __builtin_bit_cast(int, src),
                                        CTRL, 0xF, 0xF, true);
    return acc + __builtin_bit_cast(float, m);
}
// keep + (send from lane^4) via ds_swizzle  (R4-proven)
__device__ __forceinline__ float add_xor4(float keep, float send) {
    int m = __builtin_amdgcn_ds_swizzle(__builtin_bit_cast(int, send), 0x101F);
    return keep + __builtin_bit_cast(float, m);
}

// ---- R4-proven select-butterfly over j (lane bits 0-3). Lane j ends with
// the full 16-lane sum for t-phase j (identity map). BYTE-IDENTICAL to R4/R8.
__device__ __forceinline__ float butterfly16(const float (&v)[16], int j) {
    const bool q0 = (j & 1) != 0;
    const bool q1 = (j & 2) != 0;
    const bool q2 = (j & 4) != 0;
    const bool q3 = (j & 8) != 0;
    float u[8];
#pragma unroll
    for (int p = 0; p < 8; ++p) {
        float keep = q0 ? v[2 * p + 1] : v[2 * p];
        float send = q0 ? v[2 * p]     : v[2 * p + 1];
        u[p] = add_dpp<0xB1>(keep, send);            // quad_perm xor1
    }
    float w[4];
#pragma unroll
    for (int p = 0; p < 4; ++p) {
        float keep = q1 ? u[2 * p + 1] : u[2 * p];
        float send = q1 ? u[2 * p]     : u[2 * p + 1];
        w[p] = add_dpp<0x4E>(keep, send);            // quad_perm xor2
    }
    float z[2];
#pragma unroll
    for (int p = 0; p < 2; ++p) {
        float keep = q3 ? w[p + 2] : w[p];
        float send = q3 ? w[p]     : w[p + 2];
        z[p] = add_dpp<0x128>(keep, send);           // row_ror:8 == xor8
    }
    float keep = q2 ? z[1] : z[0];
    float send = q2 ? z[0] : z[1];
    return add_xor4(keep, send);                     // xor4 via ds_swizzle
}

// ------------- prep: per-row block lists, deterministic (no atomics) -------
__global__ void lti_build_lists(const int* __restrict__ rows,
                                int* __restrict__ cnt,
                                int* __restrict__ list) {
    int r = threadIdx.x;            // one thread per output row, single WG
    if (r >= NB) return;
    int m = 0;
    for (int n = 0; n < NNZ; ++n)
        if (rows[n] == r && m < MAXM) list[r * MAXM + m++] = n;
    cnt[r] = m;
}

// ------------- prep: LPT schedule — rows sorted by descending cnt ----------
__global__ void lti_rank(const int* __restrict__ cnt, int* __restrict__ perm) {
    __shared__ int sc[NB];
    const int r = threadIdx.x;       // one WG of 256 threads
    sc[r] = cnt[r];
    __syncthreads();
    const int my = sc[r];
    int rank = 0;
    for (int q = 0; q < NB; ++q) {
        int cq = sc[q];
        if (cq > my || (cq == my && q < r)) ++rank;
    }
    perm[rank] = r;                  // bijective, deterministic
}

// ------------- prep: transpose x -> xt4[b][cblk][tq][j] (float4 over t) ----
__global__ __launch_bounds__(256) void lti_transpose(
    const float* __restrict__ x, float4* __restrict__ xt4) {
    const int c  = blockIdx.x;       // channel block
    const int b  = blockIdx.y;
    const int t0 = blockIdx.z * 256;
    const int tid = threadIdx.x;

    __shared__ __align__(16) float xs[16 * 264];   // stride 264

    // stage x[b, c*16+row, t0 .. t0+255], coalesced float4
#pragma unroll
    for (int k = 0; k < 4; ++k) {
        const int f    = tid + k * 256;     // 0..1023
        const int row  = f >> 6;            // 0..15
        const int col4 = f & 63;            // 0..63
        *(float4*)&xs[row * 264 + col4 * 4] =
            *(const float4*)(x + ((size_t)b * CC + (size_t)c * BS + row) * TT
                               + t0 + col4 * 4);
    }
    __syncthreads();

    // write xt4[(b*NB+c)*8192 + tq*16 + j] = x[j][t0+4tq .. +3]
    const int j   = tid & 15;
    const int tql = tid >> 4;               // 0..15
    const size_t base = (size_t)(b * NB + c) * 8192 + (size_t)(t0 >> 2) * 16;
#pragma unroll
    for (int tb = 0; tb < 4; ++tb) {
        const int tq = tb * 16 + tql;       // 0..63 (local)
        float4 V = *(const float4*)&xs[j * 264 + 4 * tq];
        xt4[base + (size_t)tq * 16 + j] = V;   // addr = base + tb*256 + tid
    }
}

// ------------- router: one WG per (row-block, batch); t serial 0..2047 -----
// Zero LDS, zero barriers, zero Horner: state s carries across all of T
// (exact full convolution). RMW accumulation over the row's blocks; each
// address touched by exactly one lane of one WG -> no races, and bi==0
// initializes (runoff + y) so graph replays are deterministic.
__global__ __launch_bounds__(256) void lti_router_t(
    const float* __restrict__ x,       // runoff [B, C, T]
    const float* __restrict__ params,  // [NNZ, BS, BS]
    const int* __restrict__ cols,      // [NNZ]
    const int* __restrict__ cnt,       // [NB]
    const int* __restrict__ list,      // [NB, MAXM]
    const int* __restrict__ perm,      // [NB] LPT order
    const float4* __restrict__ xt4,    // transposed input
    float* __restrict__ out)           // [B, C, T]
{
    const int r   = perm[blockIdx.x];
    const int b   = blockIdx.y;
    const int tid = threadIdx.x;
    const int j   = tid & 15;          // input row within block (lane bits 0-3)
    const int i   = tid >> 4;          // output row within block (0..15)

    const size_t rowoff = ((size_t)b * CC + (size_t)r * BS + i) * TT;
    const float* __restrict__ xr   = x + rowoff;
    float* __restrict__       orow = out + rowoff;

    const int m = cnt[r];
    if (m == 0) {                      // identity rows
        for (int p = 0; p < 128; ++p) {
            const int t = p * 16 + j;
            orow[t] = xr[t];
        }
        return;
    }

    for (int bi = 0; bi < m; ++bi) {
        const int n = list[r * MAXM + bi];
        const int c = cols[n];

        const float pv  = params[n * (BS * BS) + tid];
        const float tau = 1.0f + 19.0f * pv;
        const float a   = __expf(-1.0f / tau);
        const float oma = 1.0f - a;

        const float4* __restrict__ xb4 = xt4 + (size_t)(b * NB + c) * 8192 + j;
        const float* __restrict__ prevs = (bi == 0) ? xr : orow;

        float s = 0.0f;
        for (int p = 0; p < 128; ++p) {
            // 4 coalesced float4 loads: x[j][16p .. 16p+15]
            float4 X0 = xb4[(size_t)(4 * p + 0) * 16];
            float4 X1 = xb4[(size_t)(4 * p + 1) * 16];
            float4 X2 = xb4[(size_t)(4 * p + 2) * 16];
            float4 X3 = xb4[(size_t)(4 * p + 3) * 16];

            float v[16];
            s = fmaf(a, s, X0.x); v[0]  = oma * s;
            s = fmaf(a, s, X0.y); v[1]  = oma * s;
            s = fmaf(a, s, X0.z); v[2]  = oma * s;
            s = fmaf(a, s, X0.w); v[3]  = oma * s;
            s = fmaf(a, s, X1.x); v[4]  = oma * s;
            s = fmaf(a, s, X1.y); v[5]  = oma * s;
            s = fmaf(a, s, X1.z); v[6]  = oma * s;
            s = fmaf(a, s, X1.w); v[7]  = oma * s;
            s = fmaf(a, s, X2.x); v[8]  = oma * s;
            s = fmaf(a, s, X2.y); v[9]  = oma * s;
            s = fmaf(a, s, X2.z); v[10] = oma * s;
            s = fmaf(a, s, X2.w); v[11] = oma * s;
            s = fmaf(a, s, X3.x); v[12] = oma * s;
            s = fmaf(a, s, X3.y); v[13] = oma * s;
            s = fmaf(a, s, X3.z); v[14] = oma * s;
            s = fmaf(a, s, X3.w); v[15] = oma * s;

            const float y = butterfly16(v, j);   // lane j: y[i][16p+j]
            const int t = p * 16 + j;
            orow[t] = prevs[t] + y;              // coalesced RMW, same-lane dep
        }
    }
}

// ===================== R4-proven FALLBACK path (ws too small) ==============
#define FTC 256
#define FNCH (TT / FTC)
#define FWPAD 128
#define FSSTR 388

__global__ __launch_bounds__(256) void lti_router_fb(
    const float* __restrict__ x, const float* __restrict__ params,
    const int* __restrict__ cols, const int* __restrict__ cnt,
    const int* __restrict__ list, float* __restrict__ out)
{
    const int r   = blockIdx.x;
    const int b   = blockIdx.y;
    const int t0  = blockIdx.z * FTC;
    const int tid = threadIdx.x;
    const int j   = tid & 15;
    const int i   = tid >> 4;

    __shared__ __align__(16) float xs[16 * FSSTR];

    float acc[16];
#pragma unroll
    for (int p = 0; p < 16; ++p) acc[p] = 0.0f;

    const int m = cnt[r];
    for (int bi = 0; bi < m; ++bi) {
        const int n = list[r * MAXM + bi];
        const int c = cols[n];
        const float* __restrict__ xb =
            x + ((size_t)b * CC + (size_t)c * BS) * TT;
#pragma unroll
        for (int k = 0; k < 6; ++k) {
            const int f    = tid + k * 256;
            const int row  = f / 96;
            const int col4 = f - row * 96;
            const int t    = t0 - FWPAD + col4 * 4;
            float4 v;
            if (t >= 0) v = *(const float4*)(xb + (size_t)row * TT + t);
            else        v = make_float4(0.f, 0.f, 0.f, 0.f);
            *(float4*)&xs[row * FSSTR + col4 * 4] = v;
        }
        __syncthreads();

        const float pv  = params[n * (BS * BS) + tid];
        const float tau = 1.0f + 19.0f * pv;
        const float av  = __expf(-1.0f / tau);
        const float oma = 1.0f - av;

        const float* __restrict__ xj = &xs[j * FSSTR];
        float s = 0.0f;
        if (t0 != 0) {
#pragma unroll 5
            for (int q = 0; q < 25; ++q) {
                float4 h = *(const float4*)(xj + 28 + 4 * q);
                s = fmaf(av, s, h.x); s = fmaf(av, s, h.y);
                s = fmaf(av, s, h.z); s = fmaf(av, s, h.w);
            }
        }
        const float* __restrict__ xm = xj + FWPAD;
#pragma unroll
        for (int tb = 0; tb < 16; ++tb) {
            float4 V0 = *(const float4*)(xm + tb * 16 + 0);
            float4 V1 = *(const float4*)(xm + tb * 16 + 4);
            float4 V2 = *(const float4*)(xm + tb * 16 + 8);
            float4 V3 = *(const float4*)(xm + tb * 16 + 12);
            float v[16];
            v[0]=V0.x;  v[1]=V0.y;  v[2]=V0.z;  v[3]=V0.w;
            v[4]=V1.x;  v[5]=V1.y;  v[6]=V1.z;  v[7]=V1.w;
            v[8]=V2.x;  v[9]=V2.y;  v[10]=V2.z; v[11]=V2.w;
            v[12]=V3.x; v[13]=V3.y; v[14]=V3.z; v[15]=V3.w;
#pragma unroll
            for (int t = 0; t < 16; ++t) { s = fmaf(av, s, v[t]); v[t] = oma * s; }
            acc[tb] += butterfly16(v, j);
        }
        __syncthreads();
    }

    const size_t obase = ((size_t)b * CC + (size_t)r * BS + i) * TT + t0;
#pragma unroll
    for (int p = 0; p < 16; ++p) {
        const int t = p * 16 + j;
        out[obase + t] = x[obase + t] + acc[p];
    }
}

extern "C" void kernel_launch(void* const* d_in, const int* in_sizes, int n_in,
                              void* d_out, int out_size, void* d_ws, size_t ws_size,
                              hipStream_t stream) {
    const float* runoff = (const float*)d_in[0];
    const float* params = (const float*)d_in[1];
    const int* rows = (const int*)d_in[2];
    const int* cols = (const int*)d_in[3];
    float* out = (float*)d_out;

    if (ws_size >= WS_NEED) {
        int*    cnt  = (int*)((char*)d_ws + WS_CNT);
        int*    perm = (int*)((char*)d_ws + WS_PERM);
        int*    list = (int*)((char*)d_ws + WS_LIST);
        float4* xt4  = (float4*)((char*)d_ws + WS_XT);

        lti_build_lists<<<1, 256, 0, stream>>>(rows, cnt, list);
        lti_rank<<<1, 256, 0, stream>>>(cnt, perm);
        dim3 tgrid(NB, BB, TT / 256);
        lti_transpose<<<tgrid, 256, 0, stream>>>(runoff, xt4);
        dim3 rgrid(NB, BB);
        lti_router_t<<<rgrid, 256, 0, stream>>>(runoff, params, cols, cnt,
                                                list, perm, xt4, out);
    } else {
        int* cnt  = (int*)d_ws;
        int* list = (int*)((char*)d_ws + 1024);
        lti_build_lists<<<1, 256, 0, stream>>>(rows, cnt, list);
        dim3 grid(NB, BB, FNCH);
        lti_router_fb<<<grid, 256, 0, stream>>>(runoff, params, cols, cnt,
                                                list, out);
    }
}

// Round 10
// 705.825 us; speedup vs baseline: 1.5868x; 1.5868x over previous
//
#include <hip/hip_runtime.h>

// Problem dims (fixed by the reference)
#define BB 4        // batch
#define CC 4096     // channels
#define TT 2048     // timesteps
#define BS 16       // block size
#define KK 100      // IRF taps
#define NNZ 1024    // nonzero blocks
#define NB (CC / BS)
#define MAXM 64     // max blocks per output row
#define TC 256      // timestep chunk per WG
#define NCH (TT / TC)
#define SSTR 260    // LDS row stride in floats (mod 32 == 4, 16B-aligned)

// ---------------- ws layout ----------------
#define WS_CNT   0u
#define WS_PERM  1024u
#define WS_LIST  2048u                          // 64 KB
#define WS_S0    1048576u                       // 1 MB, aligned
#define S0_BYTES ((size_t)NNZ * BB * NCH * 256 * 4)   // 33.55 MB
#define WS_NEED  ((size_t)WS_S0 + S0_BYTES)

// acc + DPP-permuted src (GCNDPPCombine fuses mov_dpp+add -> v_add_f32_dpp)
template <int CTRL>
__device__ __forceinline__ float add_dpp(float acc, float src) {
    int m = __builtin_amdgcn_update_dpp(0, __builtin_bit_cast(int, src),
                                        CTRL, 0xF, 0xF, true);
    return acc + __builtin_bit_cast(float, m);
}
// keep + (send from lane^4) via ds_swizzle  (R4-proven)
__device__ __forceinline__ float add_xor4(float keep, float send) {
    int m = __builtin_amdgcn_ds_swizzle(__builtin_bit_cast(int, send), 0x101F);
    return keep + __builtin_bit_cast(float, m);
}

// ---- R4-proven select-butterfly over j (lane bits 0-3). Lane j ends with
// the full 16-lane sum for t-phase j (identity map). BYTE-IDENTICAL to R4/R8.
__device__ __forceinline__ float butterfly16(const float (&v)[16], int j) {
    const bool q0 = (j & 1) != 0;
    const bool q1 = (j & 2) != 0;
    const bool q2 = (j & 4) != 0;
    const bool q3 = (j & 8) != 0;
    float u[8];
#pragma unroll
    for (int p = 0; p < 8; ++p) {
        float keep = q0 ? v[2 * p + 1] : v[2 * p];
        float send = q0 ? v[2 * p]     : v[2 * p + 1];
        u[p] = add_dpp<0xB1>(keep, send);            // quad_perm xor1
    }
    float w[4];
#pragma unroll
    for (int p = 0; p < 4; ++p) {
        float keep = q1 ? u[2 * p + 1] : u[2 * p];
        float send = q1 ? u[2 * p]     : u[2 * p + 1];
        w[p] = add_dpp<0x4E>(keep, send);            // quad_perm xor2
    }
    float z[2];
#pragma unroll
    for (int p = 0; p < 2; ++p) {
        float keep = q3 ? w[p + 2] : w[p];
        float send = q3 ? w[p]     : w[p + 2];
        z[p] = add_dpp<0x128>(keep, send);           // row_ror:8 == xor8
    }
    float keep = q2 ? z[1] : z[0];
    float send = q2 ? z[0] : z[1];
    return add_xor4(keep, send);                     // xor4 via ds_swizzle
}

// ------------- prep: per-row block lists, deterministic (no atomics) -------
__global__ void lti_build_lists(const int* __restrict__ rows,
                                int* __restrict__ cnt,
                                int* __restrict__ list) {
    int r = threadIdx.x;            // one thread per output row, single WG
    if (r >= NB) return;
    int m = 0;
    for (int n = 0; n < NNZ; ++n)
        if (rows[n] == r && m < MAXM) list[r * MAXM + m++] = n;
    cnt[r] = m;
}

// ------------- prep: LPT schedule — rows sorted by descending cnt ----------
__global__ void lti_rank(const int* __restrict__ cnt, int* __restrict__ perm) {
    __shared__ int sc[NB];
    const int r = threadIdx.x;       // one WG of 256 threads
    sc[r] = cnt[r];
    __syncthreads();
    const int my = sc[r];
    int rank = 0;
    for (int q = 0; q < NB; ++q) {
        int cq = sc[q];
        if (cq > my || (cq == my && q < r)) ++rank;
    }
    perm[rank] = r;                  // bijective, deterministic
}

// ------------- prep: bootstrap states s0[n][b][ch][tid] -------------------
// Bit-identical fmaf chain to the R4-proven in-router Horner: taps ascending
// over [ch*TC-100, ch*TC-1]. ch=0 -> 0.
__global__ __launch_bounds__(256) void lti_bootstrap(
    const float* __restrict__ x, const float* __restrict__ params,
    const int* __restrict__ cols, float* __restrict__ s0)
{
    const int n = blockIdx.x;
    const int b = blockIdx.y;
    const int tid = threadIdx.x;
    const int j = tid & 15;

    const float pv  = params[n * (BS * BS) + tid];
    const float tau = 1.0f + 19.0f * pv;
    const float a   = __expf(-1.0f / tau);

    const float* __restrict__ xr =
        x + ((size_t)b * CC + (size_t)cols[n] * BS + j) * TT;
    float* __restrict__ o = s0 + ((size_t)(n * BB + b) * NCH) * 256 + tid;

    o[0] = 0.0f;
    for (int ch = 1; ch < NCH; ++ch) {
        const float4* __restrict__ hp = (const float4*)(xr + ch * TC - KK);
        float s = 0.0f;
#pragma unroll 5
        for (int q = 0; q < 25; ++q) {
            float4 h = hp[q];
            s = fmaf(a, s, h.x); s = fmaf(a, s, h.y);
            s = fmaf(a, s, h.z); s = fmaf(a, s, h.w);
        }
        o[(size_t)ch * 256] = s;
    }
}

// ------------- router: one WG per (row-block r, batch b, chunk) ------------
// Double-buffered LDS staging with T14 split (prefetch next block's tile +
// params + s0 into regs BEFORE computing current), ONE barrier per visit.
__global__ __launch_bounds__(256) void lti_router(
    const float* __restrict__ x,       // runoff [B, C, T]
    const float* __restrict__ params,  // [NNZ, BS, BS]
    const int* __restrict__ cols,      // [NNZ]
    const int* __restrict__ cnt,       // [NB]
    const int* __restrict__ list,      // [NB, MAXM]
    const int* __restrict__ perm,      // [NB] LPT order
    const float* __restrict__ s0,      // bootstrap states
    float* __restrict__ out)           // [B, C, T]
{
    const int r   = perm[blockIdx.x];
    const int b   = blockIdx.y;
    const int ch  = blockIdx.z;
    const int t0  = ch * TC;
    const int tid = threadIdx.x;
    const int j    = tid & 15;         // input row within block
    const int i    = tid >> 4;         // output row within block
    const int lane = tid & 63;
    const int wv   = tid >> 6;         // wave id (staging row base)

    __shared__ __align__(16) float xs[2][16 * SSTR];

    float acc[16];
#pragma unroll
    for (int p = 0; p < 16; ++p) acc[p] = 0.0f;

    const int m = cnt[r];

    // ---- prologue: stage block 0 into buf 0; fetch its params/s0 ----
    int   n   = (m > 0) ? list[r * MAXM] : 0;
    float pv  = params[n * (BS * BS) + tid];
    float s0v = s0[((size_t)(n * BB + b) * NCH + ch) * 256 + tid];
    if (m > 0) {
        const float* __restrict__ xb =
            x + ((size_t)b * CC + (size_t)cols[n] * BS) * TT;
#pragma unroll
        for (int k = 0; k < 4; ++k) {
            const int row = wv + 4 * k;      // wave-uniform row
            float4 V = *(const float4*)(xb + (size_t)row * TT + t0 + lane * 4);
            *(float4*)&xs[0][row * SSTR + lane * 4] = V;
        }
    }
    float a   = __expf(-1.0f / (1.0f + 19.0f * pv));
    float oma = 1.0f - a;
    __syncthreads();

    for (int bi = 0; bi < m; ++bi) {
        // ---- prefetch next block (global -> regs), hidden under compute ----
        const bool has = (bi + 1 < m);
        float pvN = 0.0f, s0N = 0.0f;
        float4 XN0, XN1, XN2, XN3;
        if (has) {
            const int nN = list[r * MAXM + bi + 1];
            pvN = params[nN * (BS * BS) + tid];
            s0N = s0[((size_t)(nN * BB + b) * NCH + ch) * 256 + tid];
            const float* __restrict__ xbN =
                x + ((size_t)b * CC + (size_t)cols[nN] * BS) * TT;
            XN0 = *(const float4*)(xbN + (size_t)(wv +  0) * TT + t0 + lane * 4);
            XN1 = *(const float4*)(xbN + (size_t)(wv +  4) * TT + t0 + lane * 4);
            XN2 = *(const float4*)(xbN + (size_t)(wv +  8) * TT + t0 + lane * 4);
            XN3 = *(const float4*)(xbN + (size_t)(wv + 12) * TT + t0 + lane * 4);
        }

        // ---- compute current buffer (R4-proven inner loop) ----
        const float* __restrict__ xj = &xs[bi & 1][j * SSTR];
        float s = s0v;
#pragma unroll
        for (int tb = 0; tb < 16; ++tb) {
            float4 V0 = *(const float4*)(xj + tb * 16 + 0);
            float4 V1 = *(const float4*)(xj + tb * 16 + 4);
            float4 V2 = *(const float4*)(xj + tb * 16 + 8);
            float4 V3 = *(const float4*)(xj + tb * 16 + 12);
            float v[16];
            v[0]=V0.x;  v[1]=V0.y;  v[2]=V0.z;  v[3]=V0.w;
            v[4]=V1.x;  v[5]=V1.y;  v[6]=V1.z;  v[7]=V1.w;
            v[8]=V2.x;  v[9]=V2.y;  v[10]=V2.z; v[11]=V2.w;
            v[12]=V3.x; v[13]=V3.y; v[14]=V3.z; v[15]=V3.w;
#pragma unroll
            for (int t = 0; t < 16; ++t) {
                s = fmaf(a, s, v[t]);
                v[t] = oma * s;
            }
            acc[tb] += butterfly16(v, j);
        }

        // ---- write-late: next tile into the other buffer ----
        if (has) {
            float* __restrict__ dst = &xs[(bi + 1) & 1][0];
            *(float4*)&dst[(wv +  0) * SSTR + lane * 4] = XN0;
            *(float4*)&dst[(wv +  4) * SSTR + lane * 4] = XN1;
            *(float4*)&dst[(wv +  8) * SSTR + lane * 4] = XN2;
            *(float4*)&dst[(wv + 12) * SSTR + lane * 4] = XN3;
            pv = pvN; s0v = s0N;
            a   = __expf(-1.0f / (1.0f + 19.0f * pv));
            oma = 1.0f - a;
        }
        __syncthreads();   // readers of cur & writers of next both done
    }

    // ---- epilogue: out = runoff + y (R4-proven) ----
    const size_t obase = ((size_t)b * CC + (size_t)r * BS + i) * TT + t0;
#pragma unroll
    for (int p = 0; p < 16; ++p) {
        const int t = p * 16 + j;
        out[obase + t] = x[obase + t] + acc[p];
    }
}

// ===================== R4-proven FALLBACK path (ws too small) ==============
#define FTC 256
#define FNCH (TT / FTC)
#define FWPAD 128
#define FSSTR 388

__global__ __launch_bounds__(256) void lti_router_fb(
    const float* __restrict__ x, const float* __restrict__ params,
    const int* __restrict__ cols, const int* __restrict__ cnt,
    const int* __restrict__ list, float* __restrict__ out)
{
    const int r   = blockIdx.x;
    const int b   = blockIdx.y;
    const int t0  = blockIdx.z * FTC;
    const int tid = threadIdx.x;
    const int j   = tid & 15;
    const int i   = tid >> 4;

    __shared__ __align__(16) float xs[16 * FSSTR];

    float acc[16];
#pragma unroll
    for (int p = 0; p < 16; ++p) acc[p] = 0.0f;

    const int m = cnt[r];
    for (int bi = 0; bi < m; ++bi) {
        const int n = list[r * MAXM + bi];
        const int c = cols[n];
        const float* __restrict__ xb =
            x + ((size_t)b * CC + (size_t)c * BS) * TT;
#pragma unroll
        for (int k = 0; k < 6; ++k) {
            const int f    = tid + k * 256;
            const int row  = f / 96;
            const int col4 = f - row * 96;
            const int t    = t0 - FWPAD + col4 * 4;
            float4 v;
            if (t >= 0) v = *(const float4*)(xb + (size_t)row * TT + t);
            else        v = make_float4(0.f, 0.f, 0.f, 0.f);
            *(float4*)&xs[row * FSSTR + col4 * 4] = v;
        }
        __syncthreads();

        const float pv  = params[n * (BS * BS) + tid];
        const float tau = 1.0f + 19.0f * pv;
        const float av  = __expf(-1.0f / tau);
        const float oma = 1.0f - av;

        const float* __restrict__ xj = &xs[j * FSSTR];
        float s = 0.0f;
        if (t0 != 0) {
#pragma unroll 5
            for (int q = 0; q < 25; ++q) {
                float4 h = *(const float4*)(xj + 28 + 4 * q);
                s = fmaf(av, s, h.x); s = fmaf(av, s, h.y);
                s = fmaf(av, s, h.z); s = fmaf(av, s, h.w);
            }
        }
        const float* __restrict__ xm = xj + FWPAD;
#pragma unroll
        for (int tb = 0; tb < 16; ++tb) {
            float4 V0 = *(const float4*)(xm + tb * 16 + 0);
            float4 V1 = *(const float4*)(xm + tb * 16 + 4);
            float4 V2 = *(const float4*)(xm + tb * 16 + 8);
            float4 V3 = *(const float4*)(xm + tb * 16 + 12);
            float v[16];
            v[0]=V0.x;  v[1]=V0.y;  v[2]=V0.z;  v[3]=V0.w;
            v[4]=V1.x;  v[5]=V1.y;  v[6]=V1.z;  v[7]=V1.w;
            v[8]=V2.x;  v[9]=V2.y;  v[10]=V2.z; v[11]=V2.w;
            v[12]=V3.x; v[13]=V3.y; v[14]=V3.z; v[15]=V3.w;
#pragma unroll
            for (int t = 0; t < 16; ++t) { s = fmaf(av, s, v[t]); v[t] = oma * s; }
            acc[tb] += butterfly16(v, j);
        }
        __syncthreads();
    }

    const size_t obase = ((size_t)b * CC + (size_t)r * BS + i) * TT + t0;
#pragma unroll
    for (int p = 0; p < 16; ++p) {
        const int t = p * 16 + j;
        out[obase + t] = x[obase + t] + acc[p];
    }
}

extern "C" void kernel_launch(void* const* d_in, const int* in_sizes, int n_in,
                              void* d_out, int out_size, void* d_ws, size_t ws_size,
                              hipStream_t stream) {
    const float* runoff = (const float*)d_in[0];
    const float* params = (const float*)d_in[1];
    const int* rows = (const int*)d_in[2];
    const int* cols = (const int*)d_in[3];
    float* out = (float*)d_out;

    if (ws_size >= WS_NEED) {
        int*   cnt  = (int*)((char*)d_ws + WS_CNT);
        int*   perm = (int*)((char*)d_ws + WS_PERM);
        int*   list = (int*)((char*)d_ws + WS_LIST);
        float* s0   = (float*)((char*)d_ws + WS_S0);

        lti_build_lists<<<1, 256, 0, stream>>>(rows, cnt, list);
        lti_rank<<<1, 256, 0, stream>>>(cnt, perm);
        dim3 bgrid(NNZ, BB);
        lti_bootstrap<<<bgrid, 256, 0, stream>>>(runoff, params, cols, s0);
        dim3 rgrid(NB, BB, NCH);
        lti_router<<<rgrid, 256, 0, stream>>>(runoff, params, cols, cnt,
                                              list, perm, s0, out);
    } else {
        int* cnt  = (int*)d_ws;
        int* list = (int*)((char*)d_ws + 1024);
        lti_build_lists<<<1, 256, 0, stream>>>(rows, cnt, list);
        dim3 grid(NB, BB, FNCH);
        lti_router_fb<<<grid, 256, 0, stream>>>(runoff, params, cols, cnt,
                                                list, out);
    }
}

// Round 11
// 449.946 us; speedup vs baseline: 2.4892x; 1.5687x over previous
//
#include <hip/hip_runtime.h>

// Problem dims (fixed by the reference)
#define BB 4        // batch
#define CC 4096     // channels
#define TT 2048     // timesteps
#define BS 16       // block size
#define KK 100      // IRF taps
#define NNZ 1024    // nonzero blocks
#define NB (CC / BS)
#define MAXM 64     // max blocks per output row
#define TC 256      // timestep chunk per WG
#define NCH (TT / TC)
#define SSTR 260    // LDS row stride in floats (mod 32 == 4, 16B-aligned)
#define HSTR 108    // bootstrap LDS row stride (mod 32 == 12 -> 2-way floor)

// ---------------- ws layout ----------------
#define WS_CNT   0u
#define WS_PERM  1024u
#define WS_LIST  2048u                          // 64 KB
#define WS_S0    1048576u                       // 1 MB, aligned
#define S0_BYTES ((size_t)NNZ * BB * NCH * 256 * 4)   // 33.55 MB
#define WS_NEED  ((size_t)WS_S0 + S0_BYTES)

// acc + DPP-permuted src (GCNDPPCombine fuses mov_dpp+add -> v_add_f32_dpp)
template <int CTRL>
__device__ __forceinline__ float add_dpp(float acc, float src) {
    int m = __builtin_amdgcn_update_dpp(0, __builtin_bit_cast(int, src),
                                        CTRL, 0xF, 0xF, true);
    return acc + __builtin_bit_cast(float, m);
}
// keep + (send from lane^4) via ds_swizzle  (R4-proven)
__device__ __forceinline__ float add_xor4(float keep, float send) {
    int m = __builtin_amdgcn_ds_swizzle(__builtin_bit_cast(int, send), 0x101F);
    return keep + __builtin_bit_cast(float, m);
}

// ---- R4-proven select-butterfly over j (lane bits 0-3). Lane j ends with
// the full 16-lane sum for t-phase j (identity map). BYTE-IDENTICAL to R4/R10.
__device__ __forceinline__ float butterfly16(const float (&v)[16], int j) {
    const bool q0 = (j & 1) != 0;
    const bool q1 = (j & 2) != 0;
    const bool q2 = (j & 4) != 0;
    const bool q3 = (j & 8) != 0;
    float u[8];
#pragma unroll
    for (int p = 0; p < 8; ++p) {
        float keep = q0 ? v[2 * p + 1] : v[2 * p];
        float send = q0 ? v[2 * p]     : v[2 * p + 1];
        u[p] = add_dpp<0xB1>(keep, send);            // quad_perm xor1
    }
    float w[4];
#pragma unroll
    for (int p = 0; p < 4; ++p) {
        float keep = q1 ? u[2 * p + 1] : u[2 * p];
        float send = q1 ? u[2 * p]     : u[2 * p + 1];
        w[p] = add_dpp<0x4E>(keep, send);            // quad_perm xor2
    }
    float z[2];
#pragma unroll
    for (int p = 0; p < 2; ++p) {
        float keep = q3 ? w[p + 2] : w[p];
        float send = q3 ? w[p]     : w[p + 2];
        z[p] = add_dpp<0x128>(keep, send);           // row_ror:8 == xor8
    }
    float keep = q2 ? z[1] : z[0];
    float send = q2 ? z[0] : z[1];
    return add_xor4(keep, send);                     // xor4 via ds_swizzle
}

// ------------- prep: per-row block lists, deterministic (no atomics) -------
__global__ void lti_build_lists(const int* __restrict__ rows,
                                int* __restrict__ cnt,
                                int* __restrict__ list) {
    int r = threadIdx.x;            // one thread per output row, single WG
    if (r >= NB) return;
    int m = 0;
    for (int n = 0; n < NNZ; ++n)
        if (rows[n] == r && m < MAXM) list[r * MAXM + m++] = n;
    cnt[r] = m;
}

// ------------- prep: LPT schedule — rows sorted by descending cnt ----------
__global__ void lti_rank(const int* __restrict__ cnt, int* __restrict__ perm) {
    __shared__ int sc[NB];
    const int r = threadIdx.x;       // one WG of 256 threads
    sc[r] = cnt[r];
    __syncthreads();
    const int my = sc[r];
    int rank = 0;
    for (int q = 0; q < NB; ++q) {
        int cq = sc[q];
        if (cq > my || (cq == my && q < r)) ++rank;
    }
    perm[rank] = r;                  // bijective, deterministic
}

// ------------- prep: bootstrap states s0[n][b][ch][tid], ch = 1..NCH-1 -----
// One WG per (n, b, ch): stage the 16x100 history window into LDS with
// coalesced float4 loads, then all 256 lanes run the BIT-IDENTICAL fmaf
// chain of the R4-proven Horner (taps ascending over [ch*TC-100, ch*TC-1]).
__global__ __launch_bounds__(256) void lti_bootstrap(
    const float* __restrict__ x, const float* __restrict__ params,
    const int* __restrict__ cols, float* __restrict__ s0)
{
    const int n  = blockIdx.x;
    const int b  = blockIdx.y;
    const int ch = blockIdx.z + 1;           // 1 .. NCH-1
    const int tid = threadIdx.x;
    const int j = tid & 15;

    __shared__ __align__(16) float hx[16 * HSTR];

    // stage: 400 float4 = 16 rows x 25; rows are 400B contiguous runs
    const float* __restrict__ xw =
        x + ((size_t)b * CC + (size_t)cols[n] * BS) * TT + ch * TC - KK;
    {
        const int f0 = tid;                  // 0..255
        const int row0 = f0 / 25, q0 = f0 - row0 * 25;
        if (f0 < 400) {
            *(float4*)&hx[row0 * HSTR + 4 * q0] =
                *(const float4*)(xw + (size_t)row0 * TT + 4 * q0);
        }
        const int f1 = tid + 256;            // 256..511
        const int row1 = f1 / 25, q1 = f1 - row1 * 25;
        if (f1 < 400) {
            *(float4*)&hx[row1 * HSTR + 4 * q1] =
                *(const float4*)(xw + (size_t)row1 * TT + 4 * q1);
        }
    }
    __syncthreads();

    const float pv  = params[n * (BS * BS) + tid];
    const float tau = 1.0f + 19.0f * pv;
    const float a   = __expf(-1.0f / tau);

    const float* __restrict__ hj = &hx[j * HSTR];
    float s = 0.0f;
#pragma unroll 5
    for (int q = 0; q < 25; ++q) {
        float4 h = *(const float4*)(hj + 4 * q);
        s = fmaf(a, s, h.x); s = fmaf(a, s, h.y);
        s = fmaf(a, s, h.z); s = fmaf(a, s, h.w);
    }
    s0[((size_t)(n * BB + b) * NCH + ch) * 256 + tid] = s;
}

// ------------- router: one WG per (row-block r, batch b, chunk) ------------
// R10-proven: double-buffered LDS staging with T14 split (prefetch next
// block's tile + params + s0 into regs BEFORE computing current), ONE
// barrier per visit. s0 read is skipped for ch==0 (wave-uniform).
__global__ __launch_bounds__(256) void lti_router(
    const float* __restrict__ x,       // runoff [B, C, T]
    const float* __restrict__ params,  // [NNZ, BS, BS]
    const int* __restrict__ cols,      // [NNZ]
    const int* __restrict__ cnt,       // [NB]
    const int* __restrict__ list,      // [NB, MAXM]
    const int* __restrict__ perm,      // [NB] LPT order
    const float* __restrict__ s0,      // bootstrap states (ch >= 1)
    float* __restrict__ out)           // [B, C, T]
{
    const int r   = perm[blockIdx.x];
    const int b   = blockIdx.y;
    const int ch  = blockIdx.z;
    const int t0  = ch * TC;
    const int tid = threadIdx.x;
    const int j    = tid & 15;         // input row within block
    const int i    = tid >> 4;         // output row within block
    const int lane = tid & 63;
    const int wv   = tid >> 6;         // wave id (staging row base)

    __shared__ __align__(16) float xs[2][16 * SSTR];

    float acc[16];
#pragma unroll
    for (int p = 0; p < 16; ++p) acc[p] = 0.0f;

    const int m = cnt[r];

    // ---- prologue: stage block 0 into buf 0; fetch its params/s0 ----
    int   n   = (m > 0) ? list[r * MAXM] : 0;
    float pv  = params[n * (BS * BS) + tid];
    float s0v = (ch == 0) ? 0.0f
              : s0[((size_t)(n * BB + b) * NCH + ch) * 256 + tid];
    if (m > 0) {
        const float* __restrict__ xb =
            x + ((size_t)b * CC + (size_t)cols[n] * BS) * TT;
#pragma unroll
        for (int k = 0; k < 4; ++k) {
            const int row = wv + 4 * k;      // wave-uniform row
            float4 V = *(const float4*)(xb + (size_t)row * TT + t0 + lane * 4);
            *(float4*)&xs[0][row * SSTR + lane * 4] = V;
        }
    }
    float a   = __expf(-1.0f / (1.0f + 19.0f * pv));
    float oma = 1.0f - a;
    __syncthreads();

    for (int bi = 0; bi < m; ++bi) {
        // ---- prefetch next block (global -> regs), hidden under compute ----
        const bool has = (bi + 1 < m);
        float pvN = 0.0f, s0N = 0.0f;
        float4 XN0, XN1, XN2, XN3;
        if (has) {
            const int nN = list[r * MAXM + bi + 1];
            pvN = params[nN * (BS * BS) + tid];
            s0N = (ch == 0) ? 0.0f
                : s0[((size_t)(nN * BB + b) * NCH + ch) * 256 + tid];
            const float* __restrict__ xbN =
                x + ((size_t)b * CC + (size_t)cols[nN] * BS) * TT;
            XN0 = *(const float4*)(xbN + (size_t)(wv +  0) * TT + t0 + lane * 4);
            XN1 = *(const float4*)(xbN + (size_t)(wv +  4) * TT + t0 + lane * 4);
            XN2 = *(const float4*)(xbN + (size_t)(wv +  8) * TT + t0 + lane * 4);
            XN3 = *(const float4*)(xbN + (size_t)(wv + 12) * TT + t0 + lane * 4);
        }

        // ---- compute current buffer (R4-proven inner loop) ----
        const float* __restrict__ xj = &xs[bi & 1][j * SSTR];
        float s = s0v;
#pragma unroll
        for (int tb = 0; tb < 16; ++tb) {
            float4 V0 = *(const float4*)(xj + tb * 16 + 0);
            float4 V1 = *(const float4*)(xj + tb * 16 + 4);
            float4 V2 = *(const float4*)(xj + tb * 16 + 8);
            float4 V3 = *(const float4*)(xj + tb * 16 + 12);
            float v[16];
            v[0]=V0.x;  v[1]=V0.y;  v[2]=V0.z;  v[3]=V0.w;
            v[4]=V1.x;  v[5]=V1.y;  v[6]=V1.z;  v[7]=V1.w;
            v[8]=V2.x;  v[9]=V2.y;  v[10]=V2.z; v[11]=V2.w;
            v[12]=V3.x; v[13]=V3.y; v[14]=V3.z; v[15]=V3.w;
#pragma unroll
            for (int t = 0; t < 16; ++t) {
                s = fmaf(a, s, v[t]);
                v[t] = oma * s;
            }
            acc[tb] += butterfly16(v, j);
        }

        // ---- write-late: next tile into the other buffer ----
        if (has) {
            float* __restrict__ dst = &xs[(bi + 1) & 1][0];
            *(float4*)&dst[(wv +  0) * SSTR + lane * 4] = XN0;
            *(float4*)&dst[(wv +  4) * SSTR + lane * 4] = XN1;
            *(float4*)&dst[(wv +  8) * SSTR + lane * 4] = XN2;
            *(float4*)&dst[(wv + 12) * SSTR + lane * 4] = XN3;
            pv = pvN; s0v = s0N;
            a   = __expf(-1.0f / (1.0f + 19.0f * pv));
            oma = 1.0f - a;
        }
        __syncthreads();   // readers of cur & writers of next both done
    }

    // ---- epilogue: out = runoff + y (R4-proven) ----
    const size_t obase = ((size_t)b * CC + (size_t)r * BS + i) * TT + t0;
#pragma unroll
    for (int p = 0; p < 16; ++p) {
        const int t = p * 16 + j;
        out[obase + t] = x[obase + t] + acc[p];
    }
}

// ===================== R4-proven FALLBACK path (ws too small) ==============
#define FTC 256
#define FNCH (TT / FTC)
#define FWPAD 128
#define FSSTR 388

__global__ __launch_bounds__(256) void lti_router_fb(
    const float* __restrict__ x, const float* __restrict__ params,
    const int* __restrict__ cols, const int* __restrict__ cnt,
    const int* __restrict__ list, float* __restrict__ out)
{
    const int r   = blockIdx.x;
    const int b   = blockIdx.y;
    const int t0  = blockIdx.z * FTC;
    const int tid = threadIdx.x;
    const int j   = tid & 15;
    const int i   = tid >> 4;

    __shared__ __align__(16) float xs[16 * FSSTR];

    float acc[16];
#pragma unroll
    for (int p = 0; p < 16; ++p) acc[p] = 0.0f;

    const int m = cnt[r];
    for (int bi = 0; bi < m; ++bi) {
        const int n = list[r * MAXM + bi];
        const int c = cols[n];
        const float* __restrict__ xb =
            x + ((size_t)b * CC + (size_t)c * BS) * TT;
#pragma unroll
        for (int k = 0; k < 6; ++k) {
            const int f    = tid + k * 256;
            const int row  = f / 96;
            const int col4 = f - row * 96;
            const int t    = t0 - FWPAD + col4 * 4;
            float4 v;
            if (t >= 0) v = *(const float4*)(xb + (size_t)row * TT + t);
            else        v = make_float4(0.f, 0.f, 0.f, 0.f);
            *(float4*)&xs[row * FSSTR + col4 * 4] = v;
        }
        __syncthreads();

        const float pv  = params[n * (BS * BS) + tid];
        const float tau = 1.0f + 19.0f * pv;
        const float av  = __expf(-1.0f / tau);
        const float oma = 1.0f - av;

        const float* __restrict__ xj = &xs[j * FSSTR];
        float s = 0.0f;
        if (t0 != 0) {
#pragma unroll 5
            for (int q = 0; q < 25; ++q) {
                float4 h = *(const float4*)(xj + 28 + 4 * q);
                s = fmaf(av, s, h.x); s = fmaf(av, s, h.y);
                s = fmaf(av, s, h.z); s = fmaf(av, s, h.w);
            }
        }
        const float* __restrict__ xm = xj + FWPAD;
#pragma unroll
        for (int tb = 0; tb < 16; ++tb) {
            float4 V0 = *(const float4*)(xm + tb * 16 + 0);
            float4 V1 = *(const float4*)(xm + tb * 16 + 4);
            float4 V2 = *(const float4*)(xm + tb * 16 + 8);
            float4 V3 = *(const float4*)(xm + tb * 16 + 12);
            float v[16];
            v[0]=V0.x;  v[1]=V0.y;  v[2]=V0.z;  v[3]=V0.w;
            v[4]=V1.x;  v[5]=V1.y;  v[6]=V1.z;  v[7]=V1.w;
            v[8]=V2.x;  v[9]=V2.y;  v[10]=V2.z; v[11]=V2.w;
            v[12]=V3.x; v[13]=V3.y; v[14]=V3.z; v[15]=V3.w;
#pragma unroll
            for (int t = 0; t < 16; ++t) { s = fmaf(av, s, v[t]); v[t] = oma * s; }
            acc[tb] += butterfly16(v, j);
        }
        __syncthreads();
    }

    const size_t obase = ((size_t)b * CC + (size_t)r * BS + i) * TT + t0;
#pragma unroll
    for (int p = 0; p < 16; ++p) {
        const int t = p * 16 + j;
        out[obase + t] = x[obase + t] + acc[p];
    }
}

extern "C" void kernel_launch(void* const* d_in, const int* in_sizes, int n_in,
                              void* d_out, int out_size, void* d_ws, size_t ws_size,
                              hipStream_t stream) {
    const float* runoff = (const float*)d_in[0];
    const float* params = (const float*)d_in[1];
    const int* rows = (const int*)d_in[2];
    const int* cols = (const int*)d_in[3];
    float* out = (float*)d_out;

    if (ws_size >= WS_NEED) {
        int*   cnt  = (int*)((char*)d_ws + WS_CNT);
        int*   perm = (int*)((char*)d_ws + WS_PERM);
        int*   list = (int*)((char*)d_ws + WS_LIST);
        float* s0   = (float*)((char*)d_ws + WS_S0);

        lti_build_lists<<<1, 256, 0, stream>>>(rows, cnt, list);
        lti_rank<<<1, 256, 0, stream>>>(cnt, perm);
        dim3 bgrid(NNZ, BB, NCH - 1);
        lti_bootstrap<<<bgrid, 256, 0, stream>>>(runoff, params, cols, s0);
        dim3 rgrid(NB, BB, NCH);
        lti_router<<<rgrid, 256, 0, stream>>>(runoff, params, cols, cnt,
                                              list, perm, s0, out);
    } else {
        int* cnt  = (int*)d_ws;
        int* list = (int*)((char*)d_ws + 1024);
        lti_build_lists<<<1, 256, 0, stream>>>(rows, cnt, list);
        dim3 grid(NB, BB, FNCH);
        lti_router_fb<<<grid, 256, 0, stream>>>(runoff, params, cols, cnt,
                                                list, out);
    }
}

// Round 12
// 331.742 us; speedup vs baseline: 3.3761x; 1.3563x over previous
//
#include <hip/hip_runtime.h>

// Problem dims (fixed by the reference)
#define BB 4        // batch
#define CC 4096     // channels
#define TT 2048     // timesteps
#define BS 16       // block size
#define KK 100      // IRF taps
#define NNZ 1024    // nonzero blocks
#define NB (CC / BS)
#define MAXM 64     // max blocks per output row
#define TC 256      // timestep chunk per WG
#define NCH (TT / TC)
#define SSTR 260    // LDS row stride in floats (mod 32 == 4, 16B-aligned)
#define HSTR 108    // bootstrap LDS row stride

// ---------------- ws layout ----------------
#define WS_CNT   0u
#define WS_PERM  1024u
#define WS_LIST  2048u                          // 64 KB
#define WS_S0    1048576u                       // 1 MB, aligned
#define S0_BYTES ((size_t)NNZ * BB * NCH * 256 * 4)   // 33.55 MB
#define WS_NEED  ((size_t)WS_S0 + S0_BYTES)

// acc + DPP-permuted src (GCNDPPCombine fuses mov_dpp+add -> v_add_f32_dpp)
template <int CTRL>
__device__ __forceinline__ float add_dpp(float acc, float src) {
    int m = __builtin_amdgcn_update_dpp(0, __builtin_bit_cast(int, src),
                                        CTRL, 0xF, 0xF, true);
    return acc + __builtin_bit_cast(float, m);
}
// keep + (send from lane^4) via ds_swizzle  (R4-proven)
__device__ __forceinline__ float add_xor4(float keep, float send) {
    int m = __builtin_amdgcn_ds_swizzle(__builtin_bit_cast(int, send), 0x101F);
    return keep + __builtin_bit_cast(float, m);
}

// ---- R4-proven select-butterfly over j (lane bits 0-3). Lane j ends with
// the full 16-lane sum for t-phase j (identity map). BYTE-IDENTICAL to R4-R11.
__device__ __forceinline__ float butterfly16(const float (&v)[16], int j) {
    const bool q0 = (j & 1) != 0;
    const bool q1 = (j & 2) != 0;
    const bool q2 = (j & 4) != 0;
    const bool q3 = (j & 8) != 0;
    float u[8];
#pragma unroll
    for (int p = 0; p < 8; ++p) {
        float keep = q0 ? v[2 * p + 1] : v[2 * p];
        float send = q0 ? v[2 * p]     : v[2 * p + 1];
        u[p] = add_dpp<0xB1>(keep, send);            // quad_perm xor1
    }
    float w[4];
#pragma unroll
    for (int p = 0; p < 4; ++p) {
        float keep = q1 ? u[2 * p + 1] : u[2 * p];
        float send = q1 ? u[2 * p]     : u[2 * p + 1];
        w[p] = add_dpp<0x4E>(keep, send);            // quad_perm xor2
    }
    float z[2];
#pragma unroll
    for (int p = 0; p < 2; ++p) {
        float keep = q3 ? w[p + 2] : w[p];
        float send = q3 ? w[p]     : w[p + 2];
        z[p] = add_dpp<0x128>(keep, send);           // row_ror:8 == xor8
    }
    float keep = q2 ? z[1] : z[0];
    float send = q2 ? z[0] : z[1];
    return add_xor4(keep, send);                     // xor4 via ds_swizzle
}

// ------------- prep: per-row block lists, parallel + deterministic ---------
// One wave per row; ballot-ordered compaction preserves ascending n.
__global__ __launch_bounds__(64) void lti_build_lists(
    const int* __restrict__ rows, int* __restrict__ cnt,
    int* __restrict__ list) {
    const int r = blockIdx.x;
    const int lane = threadIdx.x;
    int m = 0;
    for (int base = 0; base < NNZ; base += 64) {
        const int n = base + lane;
        const bool hit = (rows[n] == r);
        const unsigned long long mask = __ballot(hit);
        if (hit) {
            const int pos =
                m + __popcll(mask & ((1ull << lane) - 1ull));
            if (pos < MAXM) list[r * MAXM + pos] = n;
        }
        m += (int)__popcll(mask);
    }
    if (lane == 0) cnt[r] = (m < MAXM) ? m : MAXM;
}

// ------------- prep: LPT schedule — rows sorted by descending cnt ----------
__global__ void lti_rank(const int* __restrict__ cnt, int* __restrict__ perm) {
    __shared__ int sc[NB];
    const int r = threadIdx.x;       // one WG of 256 threads
    sc[r] = cnt[r];
    __syncthreads();
    const int my = sc[r];
    int rank = 0;
    for (int q = 0; q < NB; ++q) {
        int cq = sc[q];
        if (cq > my || (cq == my && q < r)) ++rank;
    }
    perm[rank] = r;                  // bijective, deterministic
}

// ------------- prep: bootstrap states s0[n][b][ch][tid], ch = 1..NCH-1 -----
// R11-proven: coalesced LDS staging + bit-identical Horner chain.
__global__ __launch_bounds__(256) void lti_bootstrap(
    const float* __restrict__ x, const float* __restrict__ params,
    const int* __restrict__ cols, float* __restrict__ s0)
{
    const int n  = blockIdx.x;
    const int b  = blockIdx.y;
    const int ch = blockIdx.z + 1;           // 1 .. NCH-1
    const int tid = threadIdx.x;
    const int j = tid & 15;

    __shared__ __align__(16) float hx[16 * HSTR];

    const float* __restrict__ xw =
        x + ((size_t)b * CC + (size_t)cols[n] * BS) * TT + ch * TC - KK;
    {
        const int f0 = tid;
        const int row0 = f0 / 25, q0 = f0 - row0 * 25;
        if (f0 < 400) {
            *(float4*)&hx[row0 * HSTR + 4 * q0] =
                *(const float4*)(xw + (size_t)row0 * TT + 4 * q0);
        }
        const int f1 = tid + 256;
        const int row1 = f1 / 25, q1 = f1 - row1 * 25;
        if (f1 < 400) {
            *(float4*)&hx[row1 * HSTR + 4 * q1] =
                *(const float4*)(xw + (size_t)row1 * TT + 4 * q1);
        }
    }
    __syncthreads();

    const float pv  = params[n * (BS * BS) + tid];
    const float tau = 1.0f + 19.0f * pv;
    const float a   = __expf(-1.0f / tau);

    const float* __restrict__ hj = &hx[j * HSTR];
    float s = 0.0f;
#pragma unroll 5
    for (int q = 0; q < 25; ++q) {
        float4 h = *(const float4*)(hj + 4 * q);
        s = fmaf(a, s, h.x); s = fmaf(a, s, h.y);
        s = fmaf(a, s, h.z); s = fmaf(a, s, h.w);
    }
    s0[((size_t)(n * BB + b) * NCH + ch) * 256 + tid] = s;
}

// ------------- router: one WG per (row-block r, batch b, chunk) ------------
// G=2 pairing: two blocks per pass, two interleaved recursion chains, ONE
// butterfly per tile (linearity: bf(vA)+bf(vB) == bf(vA+vB)). Double-buffered
// pair slots + T14 reg-prefetch + one barrier per pair (R11 pattern).
__global__ __launch_bounds__(256) void lti_router(
    const float* __restrict__ x,       // runoff [B, C, T]
    const float* __restrict__ params,  // [NNZ, BS, BS]
    const int* __restrict__ cols,      // [NNZ]
    const int* __restrict__ cnt,       // [NB]
    const int* __restrict__ list,      // [NB, MAXM]
    const int* __restrict__ perm,      // [NB] LPT order
    const float* __restrict__ s0,      // bootstrap states (ch >= 1)
    float* __restrict__ out)           // [B, C, T]
{
    const int r   = perm[blockIdx.x];
    const int b   = blockIdx.y;
    const int ch  = blockIdx.z;
    const int t0  = ch * TC;
    const int tid = threadIdx.x;
    const int j    = tid & 15;         // input row within block
    const int i    = tid >> 4;         // output row within block
    const int lane = tid & 63;
    const int wv   = tid >> 6;         // wave id (staging row base)

    // 4 tile slots: pair-buffer cur = slots {2cur, 2cur+1}
    __shared__ __align__(16) float xs[4][16 * SSTR];

    float acc[16];
#pragma unroll
    for (int p = 0; p < 16; ++p) acc[p] = 0.0f;

    const int m = cnt[r];
    const int pairs = (m + 1) >> 1;
    const size_t xbase = (size_t)b * CC * TT;

    // ---- prologue: stage pair 0 (B duplicates A when m odd tail) ----
    float aA = 0.f, oA = 0.f, aB = 0.f, oB = 0.f, s0A = 0.f, s0B = 0.f;
    if (m > 0) {
        const int nA = list[r * MAXM + 0];
        const bool vB = (m > 1);
        const int nB = vB ? list[r * MAXM + 1] : nA;
        const float pvA = params[nA * (BS * BS) + tid];
        const float pvB = params[nB * (BS * BS) + tid];
        s0A = (ch == 0) ? 0.0f
            : s0[((size_t)(nA * BB + b) * NCH + ch) * 256 + tid];
        s0B = (ch == 0 || !vB) ? 0.0f
            : s0[((size_t)(nB * BB + b) * NCH + ch) * 256 + tid];
        const float* __restrict__ xA = x + xbase + (size_t)cols[nA] * BS * TT;
        const float* __restrict__ xB = x + xbase + (size_t)cols[nB] * BS * TT;
#pragma unroll
        for (int k = 0; k < 4; ++k) {
            const int row = wv + 4 * k;
            *(float4*)&xs[0][row * SSTR + lane * 4] =
                *(const float4*)(xA + (size_t)row * TT + t0 + lane * 4);
            *(float4*)&xs[1][row * SSTR + lane * 4] =
                *(const float4*)(xB + (size_t)row * TT + t0 + lane * 4);
        }
        aA = __expf(-1.0f / (1.0f + 19.0f * pvA));
        oA = 1.0f - aA;
        const float aBt = __expf(-1.0f / (1.0f + 19.0f * pvB));
        aB = vB ? aBt : 0.0f;
        oB = vB ? (1.0f - aBt) : 0.0f;
    }
    __syncthreads();

    int cur = 0;
    for (int pi = 0; pi < pairs; ++pi) {
        // ---- prefetch next pair (global -> regs), hidden under compute ----
        const bool has = (pi + 1 < pairs);
        float pvNA = 0.f, pvNB = 0.f, s0NA = 0.f, s0NB = 0.f;
        bool vNB = false;
        float4 XA0, XA1, XA2, XA3, XB0, XB1, XB2, XB3;
        if (has) {
            const int ia = 2 * (pi + 1);
            const int nA = list[r * MAXM + ia];
            vNB = (ia + 1 < m);
            const int nB = vNB ? list[r * MAXM + ia + 1] : nA;
            pvNA = params[nA * (BS * BS) + tid];
            pvNB = params[nB * (BS * BS) + tid];
            s0NA = (ch == 0) ? 0.0f
                 : s0[((size_t)(nA * BB + b) * NCH + ch) * 256 + tid];
            s0NB = (ch == 0 || !vNB) ? 0.0f
                 : s0[((size_t)(nB * BB + b) * NCH + ch) * 256 + tid];
            const float* __restrict__ xA =
                x + xbase + (size_t)cols[nA] * BS * TT;
            const float* __restrict__ xB =
                x + xbase + (size_t)cols[nB] * BS * TT;
            XA0 = *(const float4*)(xA + (size_t)(wv +  0) * TT + t0 + lane * 4);
            XA1 = *(const float4*)(xA + (size_t)(wv +  4) * TT + t0 + lane * 4);
            XA2 = *(const float4*)(xA + (size_t)(wv +  8) * TT + t0 + lane * 4);
            XA3 = *(const float4*)(xA + (size_t)(wv + 12) * TT + t0 + lane * 4);
            XB0 = *(const float4*)(xB + (size_t)(wv +  0) * TT + t0 + lane * 4);
            XB1 = *(const float4*)(xB + (size_t)(wv +  4) * TT + t0 + lane * 4);
            XB2 = *(const float4*)(xB + (size_t)(wv +  8) * TT + t0 + lane * 4);
            XB3 = *(const float4*)(xB + (size_t)(wv + 12) * TT + t0 + lane * 4);
        }

        // ---- compute current pair: two interleaved chains, one butterfly --
        const float* __restrict__ xjA = &xs[2 * cur][j * SSTR];
        const float* __restrict__ xjB = &xs[2 * cur + 1][j * SSTR];
        float sA = s0A, sB = s0B;
#pragma unroll
        for (int tb = 0; tb < 16; ++tb) {
            float4 A0 = *(const float4*)(xjA + tb * 16 + 0);
            float4 A1 = *(const float4*)(xjA + tb * 16 + 4);
            float4 A2 = *(const float4*)(xjA + tb * 16 + 8);
            float4 A3 = *(const float4*)(xjA + tb * 16 + 12);
            float4 B0 = *(const float4*)(xjB + tb * 16 + 0);
            float4 B1 = *(const float4*)(xjB + tb * 16 + 4);
            float4 B2 = *(const float4*)(xjB + tb * 16 + 8);
            float4 B3 = *(const float4*)(xjB + tb * 16 + 12);
            float va[16], vb[16];
            va[0]=A0.x;  va[1]=A0.y;  va[2]=A0.z;  va[3]=A0.w;
            va[4]=A1.x;  va[5]=A1.y;  va[6]=A1.z;  va[7]=A1.w;
            va[8]=A2.x;  va[9]=A2.y;  va[10]=A2.z; va[11]=A2.w;
            va[12]=A3.x; va[13]=A3.y; va[14]=A3.z; va[15]=A3.w;
            vb[0]=B0.x;  vb[1]=B0.y;  vb[2]=B0.z;  vb[3]=B0.w;
            vb[4]=B1.x;  vb[5]=B1.y;  vb[6]=B1.z;  vb[7]=B1.w;
            vb[8]=B2.x;  vb[9]=B2.y;  vb[10]=B2.z; vb[11]=B2.w;
            vb[12]=B3.x; vb[13]=B3.y; vb[14]=B3.z; vb[15]=B3.w;

            float v[16];
#pragma unroll
            for (int t = 0; t < 16; ++t) {
                sA = fmaf(aA, sA, va[t]);
                sB = fmaf(aB, sB, vb[t]);
                v[t] = fmaf(oB, sB, oA * sA);
            }
            acc[tb] += butterfly16(v, j);
        }

        // ---- write-late: next pair into the other buffer ----
        if (has) {
            const int nxt = cur ^ 1;
            float* __restrict__ dA = &xs[2 * nxt][0];
            float* __restrict__ dB = &xs[2 * nxt + 1][0];
            *(float4*)&dA[(wv +  0) * SSTR + lane * 4] = XA0;
            *(float4*)&dA[(wv +  4) * SSTR + lane * 4] = XA1;
            *(float4*)&dA[(wv +  8) * SSTR + lane * 4] = XA2;
            *(float4*)&dA[(wv + 12) * SSTR + lane * 4] = XA3;
            *(float4*)&dB[(wv +  0) * SSTR + lane * 4] = XB0;
            *(float4*)&dB[(wv +  4) * SSTR + lane * 4] = XB1;
            *(float4*)&dB[(wv +  8) * SSTR + lane * 4] = XB2;
            *(float4*)&dB[(wv + 12) * SSTR + lane * 4] = XB3;
            aA = __expf(-1.0f / (1.0f + 19.0f * pvNA));
            oA = 1.0f - aA;
            const float aBt = __expf(-1.0f / (1.0f + 19.0f * pvNB));
            aB = vNB ? aBt : 0.0f;
            oB = vNB ? (1.0f - aBt) : 0.0f;
            s0A = s0NA; s0B = s0NB;
            cur = nxt;
        }
        __syncthreads();   // readers of cur & writers of next both done
    }

    // ---- epilogue: out = runoff + y (R4-proven) ----
    const size_t obase = ((size_t)b * CC + (size_t)r * BS + i) * TT + t0;
#pragma unroll
    for (int p = 0; p < 16; ++p) {
        const int t = p * 16 + j;
        out[obase + t] = x[obase + t] + acc[p];
    }
}

// ===================== R4-proven FALLBACK path (ws too small) ==============
#define FTC 256
#define FNCH (TT / FTC)
#define FWPAD 128
#define FSSTR 388

__global__ __launch_bounds__(256) void lti_router_fb(
    const float* __restrict__ x, const float* __restrict__ params,
    const int* __restrict__ cols, const int* __restrict__ cnt,
    const int* __restrict__ list, float* __restrict__ out)
{
    const int r   = blockIdx.x;
    const int b   = blockIdx.y;
    const int t0  = blockIdx.z * FTC;
    const int tid = threadIdx.x;
    const int j   = tid & 15;
    const int i   = tid >> 4;

    __shared__ __align__(16) float xs[16 * FSSTR];

    float acc[16];
#pragma unroll
    for (int p = 0; p < 16; ++p) acc[p] = 0.0f;

    const int m = cnt[r];
    for (int bi = 0; bi < m; ++bi) {
        const int n = list[r * MAXM + bi];
        const int c = cols[n];
        const float* __restrict__ xb =
            x + ((size_t)b * CC + (size_t)c * BS) * TT;
#pragma unroll
        for (int k = 0; k < 6; ++k) {
            const int f    = tid + k * 256;
            const int row  = f / 96;
            const int col4 = f - row * 96;
            const int t    = t0 - FWPAD + col4 * 4;
            float4 v;
            if (t >= 0) v = *(const float4*)(xb + (size_t)row * TT + t);
            else        v = make_float4(0.f, 0.f, 0.f, 0.f);
            *(float4*)&xs[row * FSSTR + col4 * 4] = v;
        }
        __syncthreads();

        const float pv  = params[n * (BS * BS) + tid];
        const float tau = 1.0f + 19.0f * pv;
        const float av  = __expf(-1.0f / tau);
        const float oma = 1.0f - av;

        const float* __restrict__ xj = &xs[j * FSSTR];
        float s = 0.0f;
        if (t0 != 0) {
#pragma unroll 5
            for (int q = 0; q < 25; ++q) {
                float4 h = *(const float4*)(xj + 28 + 4 * q);
                s = fmaf(av, s, h.x); s = fmaf(av, s, h.y);
                s = fmaf(av, s, h.z); s = fmaf(av, s, h.w);
            }
        }
        const float* __restrict__ xm = xj + FWPAD;
#pragma unroll
        for (int tb = 0; tb < 16; ++tb) {
            float4 V0 = *(const float4*)(xm + tb * 16 + 0);
            float4 V1 = *(const float4*)(xm + tb * 16 + 4);
            float4 V2 = *(const float4*)(xm + tb * 16 + 8);
            float4 V3 = *(const float4*)(xm + tb * 16 + 12);
            float v[16];
            v[0]=V0.x;  v[1]=V0.y;  v[2]=V0.z;  v[3]=V0.w;
            v[4]=V1.x;  v[5]=V1.y;  v[6]=V1.z;  v[7]=V1.w;
            v[8]=V2.x;  v[9]=V2.y;  v[10]=V2.z; v[11]=V2.w;
            v[12]=V3.x; v[13]=V3.y; v[14]=V3.z; v[15]=V3.w;
#pragma unroll
            for (int t = 0; t < 16; ++t) { s = fmaf(av, s, v[t]); v[t] = oma * s; }
            acc[tb] += butterfly16(v, j);
        }
        __syncthreads();
    }

    const size_t obase = ((size_t)b * CC + (size_t)r * BS + i) * TT + t0;
#pragma unroll
    for (int p = 0; p < 16; ++p) {
        const int t = p * 16 + j;
        out[obase + t] = x[obase + t] + acc[p];
    }
}

extern "C" void kernel_launch(void* const* d_in, const int* in_sizes, int n_in,
                              void* d_out, int out_size, void* d_ws, size_t ws_size,
                              hipStream_t stream) {
    const float* runoff = (const float*)d_in[0];
    const float* params = (const float*)d_in[1];
    const int* rows = (const int*)d_in[2];
    const int* cols = (const int*)d_in[3];
    float* out = (float*)d_out;

    if (ws_size >= WS_NEED) {
        int*   cnt  = (int*)((char*)d_ws + WS_CNT);
        int*   perm = (int*)((char*)d_ws + WS_PERM);
        int*   list = (int*)((char*)d_ws + WS_LIST);
        float* s0   = (float*)((char*)d_ws + WS_S0);

        lti_build_lists<<<NB, 64, 0, stream>>>(rows, cnt, list);
        lti_rank<<<1, 256, 0, stream>>>(cnt, perm);
        dim3 bgrid(NNZ, BB, NCH - 1);
        lti_bootstrap<<<bgrid, 256, 0, stream>>>(runoff, params, cols, s0);
        dim3 rgrid(NB, BB, NCH);
        lti_router<<<rgrid, 256, 0, stream>>>(runoff, params, cols, cnt,
                                              list, perm, s0, out);
    } else {
        int* cnt  = (int*)d_ws;
        int* list = (int*)((char*)d_ws + 1024);
        lti_build_lists<<<NB, 64, 0, stream>>>(rows, cnt, list);
        dim3 grid(NB, BB, FNCH);
        lti_router_fb<<<grid, 256, 0, stream>>>(runoff, params, cols, cnt,
                                                list, out);
    }
}